// Round 12
// baseline (675.983 us; speedup 1.0000x reference)
//
#include <hip/hip_runtime.h>
#include <hip/hip_bf16.h>

#define B_ 8
#define H_ 16
#define L_ 1024
#define D_ 64

typedef __attribute__((ext_vector_type(8))) short short8;
typedef __attribute__((ext_vector_type(4))) short short4v;
typedef __attribute__((ext_vector_type(4))) float floatx4;

__device__ inline short bf16s(float f) {
    union { float f; unsigned u; } un; un.f = f;
    unsigned u = un.u;
    u += 0x7FFFu + ((u >> 16) & 1u);   // round-to-nearest-even
    return (short)(u >> 16);
}
__device__ inline float bf16f(unsigned short u) {
    union { unsigned u; float f; } un; un.u = ((unsigned)u) << 16;
    return un.f;
}

__device__ inline floatx4 mfma16(short8 a, short8 b, floatx4 c) {
    return __builtin_amdgcn_mfma_f32_16x16x32_bf16(a, b, c, 0, 0, 0);
}

#define KSTR 72
#define VSTR 40
#define PSTR 40
#define KPL (32 * KSTR)
#define VPL (64 * VSTR)
#define PPL (16 * PSTR)

// ---------------------------------------------------------------------------
// Pre-pass: K fp32 -> split bf16 (hi+lo, layout [b,h,n,d]);
//           V fp32 -> bf16 hi, TRANSPOSED layout [b,h,d,n].
// ---------------------------------------------------------------------------
__launch_bounds__(256, 4)
__global__ void prep_kernel(const float* __restrict__ k,
                            const float* __restrict__ v,
                            unsigned short* __restrict__ khi,
                            unsigned short* __restrict__ klo,
                            unsigned short* __restrict__ vth) {
    __shared__ alignas(16) short vt[64 * 72];   // [d][key] padded
    const int bid = blockIdx.x;
    const int kt  = bid & 15;
    const int h   = (bid >> 4) & 15;
    const int b   = bid >> 8;
    const int tid = threadIdx.x;
    const size_t base = ((size_t)(b * H_ + h) * L_ + kt * 64) * D_;

    #pragma unroll
    for (int i = 0; i < 4; i++) {
        const int idx = (i * 256 + tid) * 4;
        const float4 f = *(const float4*)(k + base + idx);
        short4v hi, lo;
        hi[0] = bf16s(f.x); lo[0] = bf16s(f.x - bf16f((unsigned short)hi[0]));
        hi[1] = bf16s(f.y); lo[1] = bf16s(f.y - bf16f((unsigned short)hi[1]));
        hi[2] = bf16s(f.z); lo[2] = bf16s(f.z - bf16f((unsigned short)hi[2]));
        hi[3] = bf16s(f.w); lo[3] = bf16s(f.w - bf16f((unsigned short)hi[3]));
        *(short4v*)(khi + base + idx) = hi;
        *(short4v*)(klo + base + idx) = lo;
    }

    #pragma unroll
    for (int i = 0; i < 4; i++) {
        const int idx = (i * 256 + tid) * 4;
        const int key = idx >> 6;
        const int d0  = idx & 63;
        const float4 f = *(const float4*)(v + base + idx);
        vt[(d0 + 0) * 72 + key] = bf16s(f.x);
        vt[(d0 + 1) * 72 + key] = bf16s(f.y);
        vt[(d0 + 2) * 72 + key] = bf16s(f.z);
        vt[(d0 + 3) * 72 + key] = bf16s(f.w);
    }
    __syncthreads();
    #pragma unroll
    for (int i = 0; i < 2; i++) {
        const int s = i * 2048 + tid * 8;
        const int d = s >> 6;
        const int kk = s & 63;
        short8 r = *(const short8*)&vt[d * 72 + kk];
        *(short8*)(vth + ((size_t)((b * H_ + h) * D_) + d) * L_ + kt * 64 + kk) = r;
    }
}

// ---------------------------------------------------------------------------
// Fast attention, round-16: r7 structure + PREFETCH DISTANCE 2.
//  Diagnosis (r11 arithmetic): ~1700cy wall per block-tile vs ~500cy issue
//  work; K/V prefetch (L3-resident, ~600-900cy latency) is issued at tile
//  top and vmcnt-waited at the SAME tile's bottom (window ~350cy) -> the
//  barrier is load-gated every tile. r9/r10 proved cross-tile compute ILP
//  doesn't fit the register file; deeper PREFETCH costs only +24 carrier
//  VGPRs and no cross-barrier accumulator state.
//  Schedule (2x-unrolled, named E/O carrier sets per rule-#20):
//    tile t: PV(t-1) | issue loads(t+2)->freed carrier | V(t)->regs |
//            QK(t) | bias adds (depth-2 bias sets) | softmax | P wr/rd |
//            write carrier(t+1 data, issued at t-1) -> LDS | barrier
//  Load-to-wait window: 0.8 -> ~1.8 tile-times. Compiler emits counted
//  vmcnt (waits only t+1's loads; t+2's stay in flight).
//  TRIPWIRE: if VGPR stays ~64 the compiler sank the depth-2 loads (r5
//  failure mode) and the experiment is void. Expect VGPR ~88-100.
//  Arithmetic identical to r7 -> absmax unchanged.
// ---------------------------------------------------------------------------
__launch_bounds__(256, 4)
__global__ void attn_fast(const float* __restrict__ q,
                          const unsigned short* __restrict__ khi,
                          const unsigned short* __restrict__ klo,
                          const unsigned short* __restrict__ vth,
                          const void* __restrict__ mask,
                          const float* __restrict__ bias,
                          float* __restrict__ out) {
    __shared__ alignas(16) short lds_k[2 * 2 * KPL];   // [buf][hi,lo]
    __shared__ alignas(16) short lds_vt[2 * VPL];      // [buf]
    __shared__ alignas(16) short lds_p[4 * 2 * PPL];   // per-wave, double-buf
    __shared__ int s_len;

    const int bid  = blockIdx.x;
    // swizzle decode: 8 batch-blocks sharing a bias slice -> same XCD
    const int b    = (bid >> 3) & 7;
    const int p_   = ((bid >> 6) << 3) | (bid & 7);
    const int h    = p_ >> 4;
    const int mt   = p_ & 15;
    const int tid  = threadIdx.x;
    const int wave = tid >> 6;
    const int lane = tid & 63;
    const int l16  = lane & 15;
    const int quad = lane >> 4;
    short* lds_pw = lds_p + wave * (2 * PPL);

    // ---- sequence length (dtype-agnostic popcount of prefix mask) ----
    if (tid == 0) s_len = 0;
    __syncthreads();
    {
        const unsigned char* mb = (const unsigned char*)mask;
        int fmt;
        if (mb[0] == 1 && mb[1] != 0)      fmt = 0;   // u8 bool
        else if (mb[0] == 1)               fmt = 1;   // 32-bit words
        else if (mb[1] != 0)               fmt = 2;   // 16-bit
        else                               fmt = 1;
        int s = 0;
        if (fmt == 0) {
            const unsigned char* r = mb + b * L_;
            #pragma unroll
            for (int i = 0; i < 4; i++) s += (r[tid * 4 + i] != 0);
        } else if (fmt == 1) {
            const unsigned int* r = (const unsigned int*)mask + b * L_;
            #pragma unroll
            for (int i = 0; i < 4; i++) s += (r[tid * 4 + i] != 0u);
        } else {
            const unsigned short* r = (const unsigned short*)mask + b * L_;
            #pragma unroll
            for (int i = 0; i < 4; i++) s += (r[tid * 4 + i] != 0);
        }
        #pragma unroll
        for (int off = 32; off; off >>= 1) s += __shfl_down(s, off);
        if (lane == 0) atomicAdd(&s_len, s);
    }
    __syncthreads();
    const int len = s_len;

    // ---- Q fragments, split inline (once per block) ----
    const int m_base = mt * 64 + wave * 16;
    const float* qp = q + ((size_t)((b * H_ + h) * L_) + (m_base + l16)) * D_;
    short8 qh[2], ql[2];
    #pragma unroll
    for (int c = 0; c < 2; c++)
        #pragma unroll
        for (int j = 0; j < 8; j++) {
            float x = qp[c * 32 + quad * 8 + j];
            short hh = bf16s(x);
            qh[c][j] = hh;
            ql[c][j] = bf16s(x - bf16f((unsigned short)hh));
        }

    floatx4 acc[4];
    float l_p[4];
    #pragma unroll
    for (int c = 0; c < 4; c++) { acc[c][0] = acc[c][1] = acc[c][2] = acc[c][3] = 0.f; }
    #pragma unroll
    for (int r = 0; r < 4; r++) l_p[r] = 0.f;

    const size_t kvoff = (size_t)((b * H_ + h) * L_) * D_;
    const size_t vtoff = (size_t)((b * H_ + h) * D_) * L_;
    const float* bias_base = bias + (size_t)h * L_ * L_
                           + (size_t)(m_base + quad * 4) * L_ + l16;

    const int ntiles = (len + 31) >> 5;     // len in [512,1024] -> >= 16

    // staging addresses (constant per thread)
    const int key_s = tid >> 3;           // 0..31
    const int d_s   = (tid & 7) * 8;      // 0..56
    const int dv    = tid >> 2;           // 0..63
    const int k8v   = (tid & 3) * 8;      // 0..24

    // depth-2 carriers: E receives loads for even tiles, O for odd tiles
    short8 khE, klE, vvE, khO, klO, vvO;
    float bE[8], bO[8];

    // pipeline registers: P frag + V frags of tile t-1 (r7 deferred-PV)
    short8 pf_prev;
    short8 vfr0, vfr1, vfr2, vfr3;

    // ---- prologue: load t0->E (write to LDS[0] now), t1->O (in flight),
    //      bias t0->bE, t1->bO ----
    {
        const size_t k0 = kvoff + (size_t)tid * 8;
        khE = *(const short8*)(khi + k0);
        klE = *(const short8*)(klo + k0);
        vvE = *(const short8*)(vth + vtoff + (size_t)dv * L_ + k8v);
        const size_t k1 = kvoff + (size_t)32 * D_ + (size_t)tid * 8;
        khO = *(const short8*)(khi + k1);
        klO = *(const short8*)(klo + k1);
        vvO = *(const short8*)(vth + vtoff + (size_t)dv * L_ + 32 + k8v);
        #pragma unroll
        for (int r = 0; r < 4; r++) {
            bE[2 * r]     = bias_base[(size_t)r * L_];
            bE[2 * r + 1] = bias_base[(size_t)r * L_ + 16];
            bO[2 * r]     = bias_base[(size_t)r * L_ + 32];
            bO[2 * r + 1] = bias_base[(size_t)r * L_ + 48];
        }
        *(short8*)&lds_k[key_s * KSTR + d_s] = khE;
        *(short8*)&lds_k[KPL + key_s * KSTR + d_s] = klE;
        *(short8*)&lds_vt[dv * VSTR + k8v] = vvE;
    }
    __syncthreads();

// One 32-key tile, prefetch distance 2.
//  BUF: LDS parity of this tile.  CFK/CFL/CFV: carrier set freed last tile,
//  receives loads(t+2).  WFK/WFL/WFV: carrier holding loads(t+1), written to
//  LDS[BUF^1] at the bottom.  CBIAS: bias set for this tile, reloaded with
//  bias(t+2) after consumption.
#define TILE_BODY(BUF, CFK, CFL, CFV, WFK, WFL, WFV, CBIAS)                    \
    {                                                                          \
        const int n0 = kt * 32;                                                \
        short* kb = lds_k + BUF * (2 * KPL);                                   \
        short* vb = lds_vt + BUF * VPL;                                        \
        short* pw = lds_pw + BUF * PPL;                                        \
                                                                               \
        /* PV(t-1): pure-register MFMAs */                                     \
        if (kt > 0) {                                                          \
            __builtin_amdgcn_s_setprio(1);                                     \
            acc[0] = mfma16(pf_prev, vfr0, acc[0]);                            \
            acc[1] = mfma16(pf_prev, vfr1, acc[1]);                            \
            acc[2] = mfma16(pf_prev, vfr2, acc[2]);                            \
            acc[3] = mfma16(pf_prev, vfr3, acc[3]);                            \
            __builtin_amdgcn_s_setprio(0);                                     \
        }                                                                      \
                                                                               \
        /* issue loads(t+2) into the freed carrier; waited at t+1 bottom */    \
        if (kt + 2 < ntiles) {                                                 \
            const size_t ksrc = kvoff + (size_t)(n0 + 64) * D_                 \
                              + (size_t)tid * 8;                               \
            CFK = *(const short8*)(khi + ksrc);                                \
            CFL = *(const short8*)(klo + ksrc);                                \
            CFV = *(const short8*)(vth + vtoff + (size_t)dv * L_               \
                                   + (n0 + 64) + k8v);                         \
        }                                                                      \
                                                                               \
        /* V(t) frags -> regs (consumed next tile; buffer not overwritten      \
           until after the next barrier -> race-free) */                       \
        vfr0 = *(const short8*)&vb[(0 * 16 + l16) * VSTR + quad * 8];          \
        vfr1 = *(const short8*)&vb[(1 * 16 + l16) * VSTR + quad * 8];          \
        vfr2 = *(const short8*)&vb[(2 * 16 + l16) * VSTR + quad * 8];          \
        vfr3 = *(const short8*)&vb[(3 * 16 + l16) * VSTR + quad * 8];          \
                                                                               \
        /* S = Q*K^T (split: qh*kh + ql*kh + qh*kl) */                         \
        floatx4 s0, s1;                                                        \
        s0[0]=s0[1]=s0[2]=s0[3]=0.f;                                           \
        s1[0]=s1[1]=s1[2]=s1[3]=0.f;                                           \
        __builtin_amdgcn_s_setprio(1);                                         \
        _Pragma("unroll")                                                      \
        for (int c = 0; c < 2; c++) {                                          \
            const int o0 = l16 * KSTR + c * 32 + quad * 8;                     \
            const int o1 = (16 + l16) * KSTR + c * 32 + quad * 8;              \
            short8 k0h = *(const short8*)&kb[o0];                              \
            short8 k1h = *(const short8*)&kb[o1];                              \
            short8 k0l = *(const short8*)&kb[KPL + o0];                        \
            short8 k1l = *(const short8*)&kb[KPL + o1];                        \
            s0 = mfma16(qh[c], k0h, s0);                                       \
            s0 = mfma16(ql[c], k0h, s0);                                       \
            s0 = mfma16(qh[c], k0l, s0);                                       \
            s1 = mfma16(qh[c], k1h, s1);                                       \
            s1 = mfma16(ql[c], k1h, s1);                                       \
            s1 = mfma16(qh[c], k1l, s1);                                       \
        }                                                                      \
        __builtin_amdgcn_s_setprio(0);                                         \
                                                                               \
        /* + bias (depth-2 reg sets), key-validity mask */                     \
        _Pragma("unroll")                                                      \
        for (int r = 0; r < 4; r++) {                                          \
            s0[r] += CBIAS[2 * r];                                             \
            s1[r] += CBIAS[2 * r + 1];                                         \
        }                                                                      \
        /* reload this bias set with bias(t+2) */                              \
        if (kt + 2 < ntiles) {                                                 \
            _Pragma("unroll")                                                  \
            for (int r = 0; r < 4; r++) {                                      \
                CBIAS[2 * r]     = bias_base[(size_t)r * L_ + n0 + 64];        \
                CBIAS[2 * r + 1] = bias_base[(size_t)r * L_ + n0 + 80];        \
            }                                                                  \
        }                                                                      \
        if (n0 + l16      >= len) { s0[0]=s0[1]=s0[2]=s0[3] = -1e30f; }        \
        if (n0 + 16 + l16 >= len) { s1[0]=s1[1]=s1[2]=s1[3] = -1e30f; }        \
                                                                               \
        /* static-max softmax; sum deferred to epilogue */                     \
        _Pragma("unroll")                                                      \
        for (int r = 0; r < 4; r++) {                                          \
            const float p0 = __expf(fminf(s0[r], 60.f));                       \
            const float p1 = __expf(fminf(s1[r], 60.f));                       \
            l_p[r] += p0 + p1;                                                 \
            const int row = quad * 4 + r;                                      \
            pw[row * PSTR + l16]      = bf16s(p0);                             \
            pw[row * PSTR + 16 + l16] = bf16s(p1);                             \
        }                                                                      \
        /* issue P(t) frag read; lands during next iteration */                \
        pf_prev = *(const short8*)&pw[l16 * PSTR + quad * 8];                  \
                                                                               \
        /* write carrier holding loads(t+1) -> other LDS buffer.               \
           Those loads were issued at tile t-1 (~1.8 tile-times ago); the      \
           compiler's counted vmcnt waits only on them, not on t+2's. */       \
        if (kt + 1 < ntiles) {                                                 \
            short* kb2 = lds_k + (BUF ^ 1) * (2 * KPL);                        \
            short* vb2 = lds_vt + (BUF ^ 1) * VPL;                             \
            *(short8*)&kb2[key_s * KSTR + d_s] = WFK;                          \
            *(short8*)&kb2[KPL + key_s * KSTR + d_s] = WFL;                    \
            *(short8*)&vb2[dv * VSTR + k8v] = WFV;                             \
        }                                                                      \
        __syncthreads();   /* single barrier per tile */                       \
    }

    int kt = 0;
    for (;;) {
        // even tile: buf 0; freed carrier E receives t+2; O (t+1) -> LDS[1]
        TILE_BODY(0, khE, klE, vvE, khO, klO, vvO, bE);
        if (++kt >= ntiles) break;
        // odd tile: buf 1; freed carrier O receives t+2; E (t+1) -> LDS[0]
        TILE_BODY(1, khO, klO, vvO, khE, klE, vvE, bO);
        if (++kt >= ntiles) break;
    }
#undef TILE_BODY

    // ---- drain: PV of the final tile ----
    {
        __builtin_amdgcn_s_setprio(1);
        acc[0] = mfma16(pf_prev, vfr0, acc[0]);
        acc[1] = mfma16(pf_prev, vfr1, acc[1]);
        acc[2] = mfma16(pf_prev, vfr2, acc[2]);
        acc[3] = mfma16(pf_prev, vfr3, acc[3]);
        __builtin_amdgcn_s_setprio(0);
    }

    // ---- epilogue: one cross-lane sum-reduce per row, normalize, store ----
    #pragma unroll
    for (int r = 0; r < 4; r++) {
        float ls = l_p[r];
        #pragma unroll
        for (int off = 8; off; off >>= 1) ls += __shfl_xor(ls, off);
        const int mg = m_base + quad * 4 + r;
        const bool valid = (mg < len);
        const float invl = (ls > 0.f) ? (1.0f / ls) : 0.f;
        float* op = out + (size_t)(b * L_ + mg) * (H_ * D_) + h * D_;
        #pragma unroll
        for (int c = 0; c < 4; c++)
            op[c * 16 + l16] = valid ? acc[c][r] * invl : 0.f;
    }
}

// ---------------------------------------------------------------------------
// Fallback (verified fp32 split path) — used if ws too small.
// ---------------------------------------------------------------------------
__launch_bounds__(256, 4)
__global__ void attn_fallback(const float* __restrict__ q,
                              const float* __restrict__ k,
                              const float* __restrict__ v,
                              const void* __restrict__ mask,
                              const float* __restrict__ bias,
                              float* __restrict__ out) {
    __shared__ alignas(16) short lds_k[2 * KPL];
    __shared__ alignas(16) short lds_vt[2 * VPL];
    __shared__ alignas(16) short lds_p[4 * 2 * PPL];
    __shared__ int s_len;

    const int bid  = blockIdx.x;
    const int mt   = bid & 15;
    const int h    = (bid >> 4) & 15;
    const int b    = bid >> 8;
    const int tid  = threadIdx.x;
    const int wave = tid >> 6;
    const int lane = tid & 63;
    const int l16  = lane & 15;
    const int quad = lane >> 4;
    short* lds_pw = lds_p + wave * (2 * PPL);

    if (tid == 0) s_len = 0;
    __syncthreads();
    {
        const unsigned char* mb = (const unsigned char*)mask;
        int fmt;
        if (mb[0] == 1 && mb[1] != 0)      fmt = 0;
        else if (mb[0] == 1)               fmt = 1;
        else if (mb[1] != 0)               fmt = 2;
        else                               fmt = 1;
        int s = 0;
        if (fmt == 0) {
            const unsigned char* r = mb + b * L_;
            for (int i = 0; i < 4; i++) s += (r[tid * 4 + i] != 0);
        } else if (fmt == 1) {
            const unsigned int* r = (const unsigned int*)mask + b * L_;
            for (int i = 0; i < 4; i++) s += (r[tid * 4 + i] != 0u);
        } else {
            const unsigned short* r = (const unsigned short*)mask + b * L_;
            for (int i = 0; i < 4; i++) s += (r[tid * 4 + i] != 0);
        }
        for (int off = 32; off; off >>= 1) s += __shfl_down(s, off);
        if (lane == 0) atomicAdd(&s_len, s);
    }
    __syncthreads();
    const int len = s_len;

    const int m_base = mt * 64 + wave * 16;
    const float* qp = q + ((size_t)((b * H_ + h) * L_) + (m_base + l16)) * D_;
    short8 qh[2], ql[2];
    for (int c = 0; c < 2; c++)
        for (int j = 0; j < 8; j++) {
            float x = qp[c * 32 + quad * 8 + j];
            short hh = bf16s(x);
            qh[c][j] = hh;
            ql[c][j] = bf16s(x - bf16f((unsigned short)hh));
        }

    floatx4 acc[4];
    float m_i[4], l_i[4];
    for (int c = 0; c < 4; c++) { acc[c][0]=acc[c][1]=acc[c][2]=acc[c][3]=0.f; }
    for (int r = 0; r < 4; r++) { m_i[r] = -1e30f; l_i[r] = 0.f; }

    const size_t kvoff = (size_t)((b * H_ + h) * L_) * D_;
    const size_t boff0 = (size_t)h * L_ * L_;
    const int ntiles = (len + 31) >> 5;

    for (int kt = 0; kt < ntiles; kt++) {
        const int n0 = kt * 32;
        __syncthreads();
        {
            const int e0  = tid * 8;
            const int key = e0 >> 6;
            const int d0  = e0 & 63;
            const float* ksrc = k + kvoff + (size_t)(n0 + key) * D_ + d0;
            const float* vsrc = v + kvoff + (size_t)(n0 + key) * D_ + d0;
            short* kdh = &lds_k[key * KSTR + d0];
            for (int i = 0; i < 8; i++) {
                float x = ksrc[i];
                short hh = bf16s(x);
                kdh[i]       = hh;
                kdh[KPL + i] = bf16s(x - bf16f((unsigned short)hh));
            }
            for (int i = 0; i < 8; i++) {
                float x = vsrc[i];
                short hh = bf16s(x);
                lds_vt[(d0 + i) * VSTR + key]       = hh;
                lds_vt[VPL + (d0 + i) * VSTR + key] = bf16s(x - bf16f((unsigned short)hh));
            }
        }
        __syncthreads();

        floatx4 s0, s1;
        s0[0]=s0[1]=s0[2]=s0[3]=0.f;
        s1[0]=s1[1]=s1[2]=s1[3]=0.f;
        for (int c = 0; c < 2; c++) {
            const int o0 = l16 * KSTR + c * 32 + quad * 8;
            const int o1 = (16 + l16) * KSTR + c * 32 + quad * 8;
            short8 k0h = *(const short8*)&lds_k[o0];
            short8 k1h = *(const short8*)&lds_k[o1];
            short8 k0l = *(const short8*)&lds_k[KPL + o0];
            short8 k1l = *(const short8*)&lds_k[KPL + o1];
            s0 = mfma16(qh[c], k0h, s0);
            s0 = mfma16(ql[c], k0h, s0);
            s0 = mfma16(qh[c], k0l, s0);
            s1 = mfma16(qh[c], k1h, s1);
            s1 = mfma16(ql[c], k1h, s1);
            s1 = mfma16(qh[c], k1l, s1);
        }

        for (int r = 0; r < 4; r++) {
            const float* bp = bias + boff0 + (size_t)(m_base + quad * 4 + r) * L_ + n0;
            s0[r] += bp[l16];
            s1[r] += bp[16 + l16];
        }
        if (n0 + l16      >= len) { s0[0]=s0[1]=s0[2]=s0[3] = -1e30f; }
        if (n0 + 16 + l16 >= len) { s1[0]=s1[1]=s1[2]=s1[3] = -1e30f; }

        for (int r = 0; r < 4; r++) {
            float mx = fmaxf(s0[r], s1[r]);
            for (int off = 8; off; off >>= 1) mx = fmaxf(mx, __shfl_xor(mx, off));
            const float mnew  = fmaxf(m_i[r], mx);
            const float alpha = __expf(m_i[r] - mnew);
            const float p0 = __expf(s0[r] - mnew);
            const float p1 = __expf(s1[r] - mnew);
            float ps = p0 + p1;
            for (int off = 8; off; off >>= 1) ps += __shfl_xor(ps, off);
            l_i[r] = l_i[r] * alpha + ps;
            m_i[r] = mnew;
            for (int c = 0; c < 4; c++) acc[c][r] *= alpha;
            const int row = quad * 4 + r;
            short h0 = bf16s(p0), h1 = bf16s(p1);
            lds_pw[row * PSTR + l16]      = h0;
            lds_pw[row * PSTR + 16 + l16] = h1;
            lds_pw[PPL + row * PSTR + l16]      = bf16s(p0 - bf16f((unsigned short)h0));
            lds_pw[PPL + row * PSTR + 16 + l16] = bf16s(p1 - bf16f((unsigned short)h1));
        }

        short8 pfh = *(const short8*)&lds_pw[l16 * PSTR + quad * 8];
        short8 pfl = *(const short8*)&lds_pw[PPL + l16 * PSTR + quad * 8];
        for (int c = 0; c < 4; c++) {
            const int vo = (c * 16 + l16) * VSTR + quad * 8;
            short8 vfh = *(const short8*)&lds_vt[vo];
            short8 vfl = *(const short8*)&lds_vt[VPL + vo];
            acc[c] = mfma16(pfh, vfh, acc[c]);
            acc[c] = mfma16(pfl, vfh, acc[c]);
            acc[c] = mfma16(pfh, vfl, acc[c]);
        }
    }

    for (int r = 0; r < 4; r++) {
        const int mg = m_base + quad * 4 + r;
        const bool valid = (mg < len);
        const float invl = (l_i[r] > 0.f) ? (1.0f / l_i[r]) : 0.f;
        float* op = out + (size_t)(b * L_ + mg) * (H_ * D_) + h * D_;
        for (int c = 0; c < 4; c++)
            op[c * 16 + l16] = valid ? acc[c][r] * invl : 0.f;
    }
}

extern "C" void kernel_launch(void* const* d_in, const int* in_sizes, int n_in,
                              void* d_out, int out_size, void* d_ws, size_t ws_size,
                              hipStream_t stream) {
    const float* q    = (const float*)d_in[0];
    const float* k    = (const float*)d_in[1];
    const float* v    = (const float*)d_in[2];
    const void*  mask = d_in[3];
    const float* bias = (const float*)d_in[4];
    float* out = (float*)d_out;

    const size_t PLANE = (size_t)B_ * H_ * L_ * D_;      // elements per plane
    const size_t need  = 3 * PLANE * sizeof(unsigned short);  // khi, klo, vth

    dim3 grid(B_ * H_ * (L_ / 64));
    if (ws_size >= need) {
        unsigned short* khi = (unsigned short*)d_ws;
        unsigned short* klo = khi + PLANE;
        unsigned short* vth = klo + PLANE;
        prep_kernel<<<grid, 256, 0, stream>>>(k, v, khi, klo, vth);
        attn_fast<<<grid, 256, 0, stream>>>(q, khi, klo, vth, mask, bias, out);
    } else {
        attn_fallback<<<grid, 256, 0, stream>>>(q, k, v, mask, bias, out);
    }
}

// Round 13
// 269.945 us; speedup vs baseline: 2.5041x; 2.5041x over previous
//
#include <hip/hip_runtime.h>
#include <hip/hip_bf16.h>

#define B_ 8
#define H_ 16
#define L_ 1024
#define D_ 64

typedef __attribute__((ext_vector_type(8))) short short8;
typedef __attribute__((ext_vector_type(4))) short short4v;
typedef __attribute__((ext_vector_type(4))) float floatx4;

__device__ inline short bf16s(float f) {
    union { float f; unsigned u; } un; un.f = f;
    unsigned u = un.u;
    u += 0x7FFFu + ((u >> 16) & 1u);   // round-to-nearest-even
    return (short)(u >> 16);
}
__device__ inline float bf16f(unsigned short u) {
    union { unsigned u; float f; } un; un.u = ((unsigned)u) << 16;
    return un.f;
}

__device__ inline floatx4 mfma16(short8 a, short8 b, floatx4 c) {
    return __builtin_amdgcn_mfma_f32_16x16x32_bf16(a, b, c, 0, 0, 0);
}

#define KSTR 72
#define VSTR 40
#define PSTR 40
#define KPL (32 * KSTR)
#define VPL (64 * VSTR)
#define PPL (16 * PSTR)

// ---------------------------------------------------------------------------
// Pre-pass: K fp32 -> split bf16 (hi+lo, layout [b,h,n,d]);
//           V fp32 -> bf16 hi, TRANSPOSED layout [b,h,d,n].
// ---------------------------------------------------------------------------
__launch_bounds__(256, 4)
__global__ void prep_kernel(const float* __restrict__ k,
                            const float* __restrict__ v,
                            unsigned short* __restrict__ khi,
                            unsigned short* __restrict__ klo,
                            unsigned short* __restrict__ vth) {
    __shared__ alignas(16) short vt[64 * 72];   // [d][key] padded
    const int bid = blockIdx.x;
    const int kt  = bid & 15;
    const int h   = (bid >> 4) & 15;
    const int b   = bid >> 8;
    const int tid = threadIdx.x;
    const size_t base = ((size_t)(b * H_ + h) * L_ + kt * 64) * D_;

    #pragma unroll
    for (int i = 0; i < 4; i++) {
        const int idx = (i * 256 + tid) * 4;
        const float4 f = *(const float4*)(k + base + idx);
        short4v hi, lo;
        hi[0] = bf16s(f.x); lo[0] = bf16s(f.x - bf16f((unsigned short)hi[0]));
        hi[1] = bf16s(f.y); lo[1] = bf16s(f.y - bf16f((unsigned short)hi[1]));
        hi[2] = bf16s(f.z); lo[2] = bf16s(f.z - bf16f((unsigned short)hi[2]));
        hi[3] = bf16s(f.w); lo[3] = bf16s(f.w - bf16f((unsigned short)hi[3]));
        *(short4v*)(khi + base + idx) = hi;
        *(short4v*)(klo + base + idx) = lo;
    }

    #pragma unroll
    for (int i = 0; i < 4; i++) {
        const int idx = (i * 256 + tid) * 4;
        const int key = idx >> 6;
        const int d0  = idx & 63;
        const float4 f = *(const float4*)(v + base + idx);
        vt[(d0 + 0) * 72 + key] = bf16s(f.x);
        vt[(d0 + 1) * 72 + key] = bf16s(f.y);
        vt[(d0 + 2) * 72 + key] = bf16s(f.z);
        vt[(d0 + 3) * 72 + key] = bf16s(f.w);
    }
    __syncthreads();
    #pragma unroll
    for (int i = 0; i < 2; i++) {
        const int s = i * 2048 + tid * 8;
        const int d = s >> 6;
        const int kk = s & 63;
        short8 r = *(const short8*)&vt[d * 72 + kk];
        *(short8*)(vth + ((size_t)((b * H_ + h) * D_) + d) * L_ + kt * 64 + kk) = r;
    }
}

// ---------------------------------------------------------------------------
// Fast attention — round-7 structure (best measured: 127.8-130.7us attn,
// reproduced twice). Round-12 post-mortem: depth-2 register prefetch spilled
// (WRITE 1.2GB) — third confirmation that multi-tile register pipelines at
// HIP source level don't survive the allocator at useful occupancy
// (r5: loads sunk; r10: 200-VGPR state; r12: ~100-VGPR state under 128 cap).
// All structural levers bracketed (occupancy r3/r4/r9, LDS traffic r4,
// barriers r1/r5, tail r6, ILP r9/r10, prefetch depth r12). This is the
// measured floor of the structure under hipcc:
//   * static-max softmax, epilogue-only reductions (r1)
//   * double-buffered LDS, reg prefetch K/V+bias depth-1, 1 barrier/tile (r1)
//   * cross-tile deferred-PV: PV(t-1) from registers at top of iter t;
//     P ds_read issued pre-barrier, lands next iteration (r7)
//   * static XCD swizzle for bias L2 locality
// ---------------------------------------------------------------------------
__launch_bounds__(256, 4)
__global__ void attn_fast(const float* __restrict__ q,
                          const unsigned short* __restrict__ khi,
                          const unsigned short* __restrict__ klo,
                          const unsigned short* __restrict__ vth,
                          const void* __restrict__ mask,
                          const float* __restrict__ bias,
                          float* __restrict__ out) {
    __shared__ alignas(16) short lds_k[2 * 2 * KPL];   // [buf][hi,lo]
    __shared__ alignas(16) short lds_vt[2 * VPL];      // [buf]
    __shared__ alignas(16) short lds_p[4 * 2 * PPL];   // per-wave, double-buf
    __shared__ int s_len;

    const int bid  = blockIdx.x;
    // swizzle decode: 8 batch-blocks sharing a bias slice -> same XCD
    const int b    = (bid >> 3) & 7;
    const int p_   = ((bid >> 6) << 3) | (bid & 7);
    const int h    = p_ >> 4;
    const int mt   = p_ & 15;
    const int tid  = threadIdx.x;
    const int wave = tid >> 6;
    const int lane = tid & 63;
    const int l16  = lane & 15;
    const int quad = lane >> 4;
    short* lds_pw = lds_p + wave * (2 * PPL);

    // ---- sequence length (dtype-agnostic popcount of prefix mask) ----
    if (tid == 0) s_len = 0;
    __syncthreads();
    {
        const unsigned char* mb = (const unsigned char*)mask;
        int fmt;
        if (mb[0] == 1 && mb[1] != 0)      fmt = 0;   // u8 bool
        else if (mb[0] == 1)               fmt = 1;   // 32-bit words
        else if (mb[1] != 0)               fmt = 2;   // 16-bit
        else                               fmt = 1;
        int s = 0;
        if (fmt == 0) {
            const unsigned char* r = mb + b * L_;
            #pragma unroll
            for (int i = 0; i < 4; i++) s += (r[tid * 4 + i] != 0);
        } else if (fmt == 1) {
            const unsigned int* r = (const unsigned int*)mask + b * L_;
            #pragma unroll
            for (int i = 0; i < 4; i++) s += (r[tid * 4 + i] != 0u);
        } else {
            const unsigned short* r = (const unsigned short*)mask + b * L_;
            #pragma unroll
            for (int i = 0; i < 4; i++) s += (r[tid * 4 + i] != 0);
        }
        #pragma unroll
        for (int off = 32; off; off >>= 1) s += __shfl_down(s, off);
        if (lane == 0) atomicAdd(&s_len, s);
    }
    __syncthreads();
    const int len = s_len;

    // ---- Q fragments, split inline (once per block) ----
    const int m_base = mt * 64 + wave * 16;
    const float* qp = q + ((size_t)((b * H_ + h) * L_) + (m_base + l16)) * D_;
    short8 qh[2], ql[2];
    #pragma unroll
    for (int c = 0; c < 2; c++)
        #pragma unroll
        for (int j = 0; j < 8; j++) {
            float x = qp[c * 32 + quad * 8 + j];
            short hh = bf16s(x);
            qh[c][j] = hh;
            ql[c][j] = bf16s(x - bf16f((unsigned short)hh));
        }

    floatx4 acc[4];
    float l_p[4];
    #pragma unroll
    for (int c = 0; c < 4; c++) { acc[c][0] = acc[c][1] = acc[c][2] = acc[c][3] = 0.f; }
    #pragma unroll
    for (int r = 0; r < 4; r++) l_p[r] = 0.f;

    const size_t kvoff = (size_t)((b * H_ + h) * L_) * D_;
    const size_t vtoff = (size_t)((b * H_ + h) * D_) * L_;
    const float* bias_base = bias + (size_t)h * L_ * L_
                           + (size_t)(m_base + quad * 4) * L_ + l16;

    const int ntiles = (len + 31) >> 5;

    // staging addresses (constant per thread)
    const int key_s = tid >> 3;           // 0..31
    const int d_s   = (tid & 7) * 8;      // 0..56
    const int dv    = tid >> 2;           // 0..63
    const int k8v   = (tid & 3) * 8;      // 0..24

    short8 kh_r, kl_r, vv_r;
    float bc[8], bn[8];

    // pipeline registers: P frag of tile t-1 (ds_read issued in iter t-1),
    // V frags of tile t-1 (loaded to regs in iter t-1; wave-invariant data)
    short8 pf_prev;
    short8 vfr0, vfr1, vfr2, vfr3;

    // ---- prologue: stage tile 0 into buffer 0, load tile-0 bias ----
    {
        const size_t ksrc = kvoff + (size_t)tid * 8;
        kh_r = *(const short8*)(khi + ksrc);
        kl_r = *(const short8*)(klo + ksrc);
        vv_r = *(const short8*)(vth + vtoff + (size_t)dv * L_ + k8v);
        #pragma unroll
        for (int r = 0; r < 4; r++) {
            bc[2 * r]     = bias_base[(size_t)r * L_];
            bc[2 * r + 1] = bias_base[(size_t)r * L_ + 16];
        }
        *(short8*)&lds_k[key_s * KSTR + d_s] = kh_r;
        *(short8*)&lds_k[KPL + key_s * KSTR + d_s] = kl_r;
        *(short8*)&lds_vt[dv * VSTR + k8v] = vv_r;
    }
    __syncthreads();

    for (int kt = 0; kt < ntiles; kt++) {
        const int n0 = kt * 32;
        short* kb = lds_k + (kt & 1) * (2 * KPL);
        short* vb = lds_vt + (kt & 1) * VPL;
        short* pw = lds_pw + (kt & 1) * PPL;
        const bool pfetch = (kt + 1 < ntiles);

        // ---- PV(t-1): pure-register MFMAs; pf_prev/vfr loaded last iter ----
        if (kt > 0) {
            __builtin_amdgcn_s_setprio(1);
            acc[0] = mfma16(pf_prev, vfr0, acc[0]);
            acc[1] = mfma16(pf_prev, vfr1, acc[1]);
            acc[2] = mfma16(pf_prev, vfr2, acc[2]);
            acc[3] = mfma16(pf_prev, vfr3, acc[3]);
            __builtin_amdgcn_s_setprio(0);
        }

        // ---- issue next tile's global loads; latency hides under tile ----
        if (pfetch) {
            const size_t ksrc = kvoff + (size_t)(n0 + 32) * D_ + (size_t)tid * 8;
            kh_r = *(const short8*)(khi + ksrc);
            kl_r = *(const short8*)(klo + ksrc);
            vv_r = *(const short8*)(vth + vtoff + (size_t)dv * L_ + (n0 + 32) + k8v);
            #pragma unroll
            for (int r = 0; r < 4; r++) {
                bn[2 * r]     = bias_base[(size_t)r * L_ + n0 + 32];
                bn[2 * r + 1] = bias_base[(size_t)r * L_ + n0 + 48];
            }
        }

        // ---- load V(t) frags into registers (consumed next iteration;
        //      slot kt&1 is not overwritten until iter t+1's staging, which
        //      is after the barrier -> race-free) ----
        vfr0 = *(const short8*)&vb[(0 * 16 + l16) * VSTR + quad * 8];
        vfr1 = *(const short8*)&vb[(1 * 16 + l16) * VSTR + quad * 8];
        vfr2 = *(const short8*)&vb[(2 * 16 + l16) * VSTR + quad * 8];
        vfr3 = *(const short8*)&vb[(3 * 16 + l16) * VSTR + quad * 8];

        // ---- S = Q*K^T (split: qh*kh + ql*kh + qh*kl) ----
        floatx4 s0, s1;
        s0[0]=s0[1]=s0[2]=s0[3]=0.f;
        s1[0]=s1[1]=s1[2]=s1[3]=0.f;
        __builtin_amdgcn_s_setprio(1);
        #pragma unroll
        for (int c = 0; c < 2; c++) {
            const int o0 = l16 * KSTR + c * 32 + quad * 8;
            const int o1 = (16 + l16) * KSTR + c * 32 + quad * 8;
            short8 k0h = *(const short8*)&kb[o0];
            short8 k1h = *(const short8*)&kb[o1];
            short8 k0l = *(const short8*)&kb[KPL + o0];
            short8 k1l = *(const short8*)&kb[KPL + o1];
            s0 = mfma16(qh[c], k0h, s0);
            s0 = mfma16(ql[c], k0h, s0);
            s0 = mfma16(qh[c], k0l, s0);
            s1 = mfma16(qh[c], k1h, s1);
            s1 = mfma16(ql[c], k1h, s1);
            s1 = mfma16(qh[c], k1l, s1);
        }
        __builtin_amdgcn_s_setprio(0);

        // ---- + bias (prefetched fp32 regs), key-validity mask ----
        #pragma unroll
        for (int r = 0; r < 4; r++) { s0[r] += bc[2 * r]; s1[r] += bc[2 * r + 1]; }
        if (n0 + l16      >= len) { s0[0]=s0[1]=s0[2]=s0[3] = -1e30f; }
        if (n0 + 16 + l16 >= len) { s1[0]=s1[1]=s1[2]=s1[3] = -1e30f; }

        // ---- static-max softmax: p = exp(s); sum deferred to epilogue ----
        #pragma unroll
        for (int r = 0; r < 4; r++) {
            const float p0 = __expf(fminf(s0[r], 60.f));
            const float p1 = __expf(fminf(s1[r], 60.f));
            l_p[r] += p0 + p1;
            const int row = quad * 4 + r;
            pw[row * PSTR + l16]      = bf16s(p0);
            pw[row * PSTR + 16 + l16] = bf16s(p1);
        }

        // ---- issue P(t) frag read; lands during next iteration ----
        pf_prev = *(const short8*)&pw[l16 * PSTR + quad * 8];

        // ---- write prefetched tile into the other buffer, swap bias regs ----
        if (pfetch) {
            short* kb2 = lds_k + ((kt + 1) & 1) * (2 * KPL);
            short* vb2 = lds_vt + ((kt + 1) & 1) * VPL;
            *(short8*)&kb2[key_s * KSTR + d_s] = kh_r;
            *(short8*)&kb2[KPL + key_s * KSTR + d_s] = kl_r;
            *(short8*)&vb2[dv * VSTR + k8v] = vv_r;
            #pragma unroll
            for (int i = 0; i < 8; i++) bc[i] = bn[i];
        }
        __syncthreads();   // single barrier per tile
    }

    // ---- drain: PV of the final tile ----
    {
        __builtin_amdgcn_s_setprio(1);
        acc[0] = mfma16(pf_prev, vfr0, acc[0]);
        acc[1] = mfma16(pf_prev, vfr1, acc[1]);
        acc[2] = mfma16(pf_prev, vfr2, acc[2]);
        acc[3] = mfma16(pf_prev, vfr3, acc[3]);
        __builtin_amdgcn_s_setprio(0);
    }

    // ---- epilogue: one cross-lane sum-reduce per row, normalize, store ----
    #pragma unroll
    for (int r = 0; r < 4; r++) {
        float ls = l_p[r];
        #pragma unroll
        for (int off = 8; off; off >>= 1) ls += __shfl_xor(ls, off);
        const int mg = m_base + quad * 4 + r;
        const bool valid = (mg < len);
        const float invl = (ls > 0.f) ? (1.0f / ls) : 0.f;
        float* op = out + (size_t)(b * L_ + mg) * (H_ * D_) + h * D_;
        #pragma unroll
        for (int c = 0; c < 4; c++)
            op[c * 16 + l16] = valid ? acc[c][r] * invl : 0.f;
    }
}

// ---------------------------------------------------------------------------
// Fallback (verified fp32 split path) — used if ws too small.
// ---------------------------------------------------------------------------
__launch_bounds__(256, 4)
__global__ void attn_fallback(const float* __restrict__ q,
                              const float* __restrict__ k,
                              const float* __restrict__ v,
                              const void* __restrict__ mask,
                              const float* __restrict__ bias,
                              float* __restrict__ out) {
    __shared__ alignas(16) short lds_k[2 * KPL];
    __shared__ alignas(16) short lds_vt[2 * VPL];
    __shared__ alignas(16) short lds_p[4 * 2 * PPL];
    __shared__ int s_len;

    const int bid  = blockIdx.x;
    const int mt   = bid & 15;
    const int h    = (bid >> 4) & 15;
    const int b    = bid >> 8;
    const int tid  = threadIdx.x;
    const int wave = tid >> 6;
    const int lane = tid & 63;
    const int l16  = lane & 15;
    const int quad = lane >> 4;
    short* lds_pw = lds_p + wave * (2 * PPL);

    if (tid == 0) s_len = 0;
    __syncthreads();
    {
        const unsigned char* mb = (const unsigned char*)mask;
        int fmt;
        if (mb[0] == 1 && mb[1] != 0)      fmt = 0;
        else if (mb[0] == 1)               fmt = 1;
        else if (mb[1] != 0)               fmt = 2;
        else                               fmt = 1;
        int s = 0;
        if (fmt == 0) {
            const unsigned char* r = mb + b * L_;
            for (int i = 0; i < 4; i++) s += (r[tid * 4 + i] != 0);
        } else if (fmt == 1) {
            const unsigned int* r = (const unsigned int*)mask + b * L_;
            for (int i = 0; i < 4; i++) s += (r[tid * 4 + i] != 0u);
        } else {
            const unsigned short* r = (const unsigned short*)mask + b * L_;
            for (int i = 0; i < 4; i++) s += (r[tid * 4 + i] != 0);
        }
        for (int off = 32; off; off >>= 1) s += __shfl_down(s, off);
        if (lane == 0) atomicAdd(&s_len, s);
    }
    __syncthreads();
    const int len = s_len;

    const int m_base = mt * 64 + wave * 16;
    const float* qp = q + ((size_t)((b * H_ + h) * L_) + (m_base + l16)) * D_;
    short8 qh[2], ql[2];
    for (int c = 0; c < 2; c++)
        for (int j = 0; j < 8; j++) {
            float x = qp[c * 32 + quad * 8 + j];
            short hh = bf16s(x);
            qh[c][j] = hh;
            ql[c][j] = bf16s(x - bf16f((unsigned short)hh));
        }

    floatx4 acc[4];
    float m_i[4], l_i[4];
    for (int c = 0; c < 4; c++) { acc[c][0]=acc[c][1]=acc[c][2]=acc[c][3]=0.f; }
    for (int r = 0; r < 4; r++) { m_i[r] = -1e30f; l_i[r] = 0.f; }

    const size_t kvoff = (size_t)((b * H_ + h) * L_) * D_;
    const size_t boff0 = (size_t)h * L_ * L_;
    const int ntiles = (len + 31) >> 5;

    for (int kt = 0; kt < ntiles; kt++) {
        const int n0 = kt * 32;
        __syncthreads();
        {
            const int e0  = tid * 8;
            const int key = e0 >> 6;
            const int d0  = e0 & 63;
            const float* ksrc = k + kvoff + (size_t)(n0 + key) * D_ + d0;
            const float* vsrc = v + kvoff + (size_t)(n0 + key) * D_ + d0;
            short* kdh = &lds_k[key * KSTR + d0];
            for (int i = 0; i < 8; i++) {
                float x = ksrc[i];
                short hh = bf16s(x);
                kdh[i]       = hh;
                kdh[KPL + i] = bf16s(x - bf16f((unsigned short)hh));
            }
            for (int i = 0; i < 8; i++) {
                float x = vsrc[i];
                short hh = bf16s(x);
                lds_vt[(d0 + i) * VSTR + key]       = hh;
                lds_vt[VPL + (d0 + i) * VSTR + key] = bf16s(x - bf16f((unsigned short)hh));
            }
        }
        __syncthreads();

        floatx4 s0, s1;
        s0[0]=s0[1]=s0[2]=s0[3]=0.f;
        s1[0]=s1[1]=s1[2]=s1[3]=0.f;
        for (int c = 0; c < 2; c++) {
            const int o0 = l16 * KSTR + c * 32 + quad * 8;
            const int o1 = (16 + l16) * KSTR + c * 32 + quad * 8;
            short8 k0h = *(const short8*)&lds_k[o0];
            short8 k1h = *(const short8*)&lds_k[o1];
            short8 k0l = *(const short8*)&lds_k[KPL + o0];
            short8 k1l = *(const short8*)&lds_k[KPL + o1];
            s0 = mfma16(qh[c], k0h, s0);
            s0 = mfma16(ql[c], k0h, s0);
            s0 = mfma16(qh[c], k0l, s0);
            s1 = mfma16(qh[c], k1h, s1);
            s1 = mfma16(ql[c], k1h, s1);
            s1 = mfma16(qh[c], k1l, s1);
        }

        for (int r = 0; r < 4; r++) {
            const float* bp = bias + boff0 + (size_t)(m_base + quad * 4 + r) * L_ + n0;
            s0[r] += bp[l16];
            s1[r] += bp[16 + l16];
        }
        if (n0 + l16      >= len) { s0[0]=s0[1]=s0[2]=s0[3] = -1e30f; }
        if (n0 + 16 + l16 >= len) { s1[0]=s1[1]=s1[2]=s1[3] = -1e30f; }

        for (int r = 0; r < 4; r++) {
            float mx = fmaxf(s0[r], s1[r]);
            for (int off = 8; off; off >>= 1) mx = fmaxf(mx, __shfl_xor(mx, off));
            const float mnew  = fmaxf(m_i[r], mx);
            const float alpha = __expf(m_i[r] - mnew);
            const float p0 = __expf(s0[r] - mnew);
            const float p1 = __expf(s1[r] - mnew);
            float ps = p0 + p1;
            for (int off = 8; off; off >>= 1) ps += __shfl_xor(ps, off);
            l_i[r] = l_i[r] * alpha + ps;
            m_i[r] = mnew;
            for (int c = 0; c < 4; c++) acc[c][r] *= alpha;
            const int row = quad * 4 + r;
            short h0 = bf16s(p0), h1 = bf16s(p1);
            lds_pw[row * PSTR + l16]      = h0;
            lds_pw[row * PSTR + 16 + l16] = h1;
            lds_pw[PPL + row * PSTR + l16]      = bf16s(p0 - bf16f((unsigned short)h0));
            lds_pw[PPL + row * PSTR + 16 + l16] = bf16s(p1 - bf16f((unsigned short)h1));
        }

        short8 pfh = *(const short8*)&lds_pw[l16 * PSTR + quad * 8];
        short8 pfl = *(const short8*)&lds_pw[PPL + l16 * PSTR + quad * 8];
        for (int c = 0; c < 4; c++) {
            const int vo = (c * 16 + l16) * VSTR + quad * 8;
            short8 vfh = *(const short8*)&lds_vt[vo];
            short8 vfl = *(const short8*)&lds_vt[VPL + vo];
            acc[c] = mfma16(pfh, vfh, acc[c]);
            acc[c] = mfma16(pfl, vfh, acc[c]);
            acc[c] = mfma16(pfh, vfl, acc[c]);
        }
    }

    for (int r = 0; r < 4; r++) {
        const int mg = m_base + quad * 4 + r;
        const bool valid = (mg < len);
        const float invl = (l_i[r] > 0.f) ? (1.0f / l_i[r]) : 0.f;
        float* op = out + (size_t)(b * L_ + mg) * (H_ * D_) + h * D_;
        for (int c = 0; c < 4; c++)
            op[c * 16 + l16] = valid ? acc[c][r] * invl : 0.f;
    }
}

extern "C" void kernel_launch(void* const* d_in, const int* in_sizes, int n_in,
                              void* d_out, int out_size, void* d_ws, size_t ws_size,
                              hipStream_t stream) {
    const float* q    = (const float*)d_in[0];
    const float* k    = (const float*)d_in[1];
    const float* v    = (const float*)d_in[2];
    const void*  mask = d_in[3];
    const float* bias = (const float*)d_in[4];
    float* out = (float*)d_out;

    const size_t PLANE = (size_t)B_ * H_ * L_ * D_;      // elements per plane
    const size_t need  = 3 * PLANE * sizeof(unsigned short);  // khi, klo, vth

    dim3 grid(B_ * H_ * (L_ / 64));
    if (ws_size >= need) {
        unsigned short* khi = (unsigned short*)d_ws;
        unsigned short* klo = khi + PLANE;
        unsigned short* vth = klo + PLANE;
        prep_kernel<<<grid, 256, 0, stream>>>(k, v, khi, klo, vth);
        attn_fast<<<grid, 256, 0, stream>>>(q, khi, klo, vth, mask, bias, out);
    } else {
        attn_fallback<<<grid, 256, 0, stream>>>(q, k, v, mask, bias, out);
    }
}